// Round 5
// baseline (951.860 us; speedup 1.0000x reference)
//
#include <hip/hip_runtime.h>
#include <hip/hip_bf16.h>
#include <stdint.h>
#include <math.h>

#define NN 50000
#define DD 128
#define EE 500000
#define ROWT 1563   // ceil(NN/32)

typedef __attribute__((ext_vector_type(8))) short bfx8;   // 8 bf16 = 4 VGPR
typedef __attribute__((ext_vector_type(4))) short bfx4;
typedef __attribute__((ext_vector_type(4))) float f32x4;

static __device__ __forceinline__ short f2bf(float f) {
  union { float f; uint32_t u; } v; v.f = f;
  uint32_t r = (v.u + 0x7fffu + ((v.u >> 16) & 1u)) >> 16;
  return (short)r;
}
static __device__ __forceinline__ float bf2f(short b) {
  union { uint32_t u; float f; } v; v.u = ((uint32_t)(uint16_t)b) << 16;
  return v.f;
}

// A-fragment from global bf16 [rows][128]
static __device__ __forceinline__ bfx8 load_frag_clamp(const short* base, int row0, int k0, int lane) {
  int r = row0 + (lane & 15);
  if (r >= NN) r = NN - 1;
  int k = k0 + ((lane >> 4) << 3);
  return *reinterpret_cast<const bfx8*>(base + (size_t)r * DD + k);
}
// B-fragment from packed weights: [ct][ks][64 lanes][8]
static __device__ __forceinline__ bfx8 load_pk(const short* p, int ct, int ks, int lane) {
  return *reinterpret_cast<const bfx8*>(p + ((((size_t)ct * 4 + ks) * 64 + lane) << 3));
}
// A-fragment from LDS f32 [32][132] -> bf16
static __device__ __forceinline__ bfx8 lds_frag(const float* A, int row0, int ks, int lane) {
  const float* p = A + (size_t)(row0 + (lane & 15)) * 132 + ks * 32 + ((lane >> 4) << 3);
  f32x4 u = *reinterpret_cast<const f32x4*>(p);
  f32x4 v = *reinterpret_cast<const f32x4*>(p + 4);
  bfx8 o;
  o[0]=f2bf(u[0]); o[1]=f2bf(u[1]); o[2]=f2bf(u[2]); o[3]=f2bf(u[3]);
  o[4]=f2bf(v[0]); o[5]=f2bf(v[1]); o[6]=f2bf(v[2]); o[7]=f2bf(v[3]);
  return o;
}

// ---------------- convert fp32 -> bf16 (x_a, x_b) ----------------
struct ConvJobs { const float* src[2]; short* dst[2]; };

__global__ __launch_bounds__(256) void k_convert(ConvJobs jobs) {
  int j = blockIdx.y;
  const float* s = jobs.src[j];
  short* d = jobs.dst[j];
  int i = (blockIdx.x * 256 + threadIdx.x) * 4;
  if (i >= NN * DD) return;
  f32x4 v = *reinterpret_cast<const f32x4*>(s + i);
  bfx4 o;
  o[0]=f2bf(v[0]); o[1]=f2bf(v[1]); o[2]=f2bf(v[2]); o[3]=f2bf(v[3]);
  *reinterpret_cast<bfx4*>(d + i) = o;
}

// ---------------- comb = wih @ Wt  (f32), [384,128] ----------------
struct CombJobs { const float* wih[3]; const float* wt[3]; float* out[3]; };

__global__ __launch_bounds__(256) void k_comb(CombJobs cj) {
  int e = blockIdx.y;
  const float* wih = cj.wih[e];
  const float* wt  = cj.wt[e];
  float* out = cj.out[e];
  int tid = blockIdx.x * 256 + threadIdx.x;
  int i = tid >> 7, j = tid & 127;
  float acc = 0.f;
  #pragma unroll 4
  for (int k = 0; k < 128; ++k) acc += wih[i * 128 + k] * wt[k * 128 + j];
  out[i * 128 + j] = acc;
}

// ---------------- pack f32 matrix [R][128] into fragment layout bf16 ----------------
struct PackJobs { const float* src[9]; short* dst[9]; int nct[9]; };

__global__ __launch_bounds__(256) void k_pack(PackJobs pj) {
  int j = blockIdx.y;
  int tid = blockIdx.x * 256 + threadIdx.x;
  if (tid >= pj.nct[j] * 256) return;
  int lane = tid & 63, ks = (tid >> 6) & 3, ct = tid >> 8;
  const float* s = pj.src[j] + (size_t)(ct * 16 + (lane & 15)) * 128 + ks * 32 + ((lane >> 4) << 3);
  bfx8 o;
  #pragma unroll
  for (int i = 0; i < 8; ++i) o[i] = f2bf(s[i]);
  *reinterpret_cast<bfx8*>(pj.dst[j] + ((size_t)tid << 3)) = o;
}

// ---------------- CSR build (batched over 3 edge types) ----------------
struct CsrArgs { const int* edge[3]; int* counts[3]; int* offs[3]; uint32_t* bucket[3]; };

__global__ __launch_bounds__(256) void k_hist(CsrArgs a) {
  int t = blockIdx.y;
  int tid = blockIdx.x * 256 + threadIdx.x;
  if (tid >= EE) return;
  atomicAdd(&a.counts[t][a.edge[t][EE + tid]], 1);
}

__global__ __launch_bounds__(1024) void k_scan(CsrArgs a) {
  const int* counts = a.counts[blockIdx.x];
  int* offs = a.offs[blockIdx.x];
  __shared__ int lds[1024];
  const int C = (NN + 1023) / 1024;   // 49
  int t = threadIdx.x;
  int base = t * C;
  int sum = 0;
  for (int i = 0; i < C; ++i) { int idx = base + i; if (idx < NN) sum += counts[idx]; }
  lds[t] = sum;
  __syncthreads();
  for (int off = 1; off < 1024; off <<= 1) {
    int v = (t >= off) ? lds[t - off] : 0;
    __syncthreads();
    lds[t] += v;
    __syncthreads();
  }
  int excl = lds[t] - sum;
  for (int i = 0; i < C; ++i) {
    int idx = base + i;
    if (idx < NN) { offs[idx] = excl; excl += counts[idx]; }
  }
}

// fill: bucket entry packs src (bits 0-19) and local row t&31 (bits 20-24)
__global__ __launch_bounds__(256) void k_fill(CsrArgs a) {
  int t = blockIdx.y;
  int tid = blockIdx.x * 256 + threadIdx.x;
  if (tid >= EE) return;
  int tgt = a.edge[t][EE + tid];
  int src = a.edge[t][tid];
  int pos = atomicAdd(&a.offs[t][tgt], 1);
  a.bucket[t][pos] = (uint32_t)src | ((uint32_t)(tgt & 31) << 20);
}

// ---------------- fused unit: gather -> agg=sum@Ws^T -> GRU -> res regs ----------------
static __device__ __forceinline__ void unit(
    int rbase, int wave, int lane,
    const int* __restrict__ offs, const uint32_t* __restrict__ bucket,
    const short* __restrict__ xsrc, const short* __restrict__ xt,
    const short* __restrict__ wsp, const short* __restrict__ combp,
    const short* __restrict__ whhp,
    const float* __restrict__ bih, const float* __restrict__ bhh,
    float* aggX, float* aggl, f32x4 (&res)[2][2]) {
  const int tid = wave * 64 + lane;

  // zero aggX
  #pragma unroll
  for (int i = tid; i < 32 * 132; i += 256) aggX[i] = 0.f;
  __syncthreads();

  // edge-parallel gather: 8-thread group per contiguous edge chunk
  {
    int eStart = rbase ? offs[rbase - 1] : 0;
    int lastRow = rbase + 31; if (lastRow >= NN) lastRow = NN - 1;
    int eEnd = offs[lastRow];
    int nE = eEnd - eStart;
    int chunk = (nE + 31) >> 5;
    int g = tid >> 3;
    int c0 = (tid & 7) * 16;
    int i0 = eStart + g * chunk;
    int i1 = i0 + chunk; if (i1 > eEnd) i1 = eEnd;
    f32x4 ac0 = (f32x4)(0.f), ac1 = (f32x4)(0.f), ac2 = (f32x4)(0.f), ac3 = (f32x4)(0.f);
    int curlr = -1;
    for (int i = i0; i < i1; ++i) {
      uint32_t e = bucket[i];
      int lr = (int)(e >> 20);
      int s  = (int)(e & 0xFFFFFu);
      if (lr != curlr) {
        if (curlr >= 0) {
          float* d = aggX + curlr * 132 + c0;
          #pragma unroll
          for (int j = 0; j < 4; ++j) atomicAdd(d + j,      ac0[j]);
          #pragma unroll
          for (int j = 0; j < 4; ++j) atomicAdd(d + 4 + j,  ac1[j]);
          #pragma unroll
          for (int j = 0; j < 4; ++j) atomicAdd(d + 8 + j,  ac2[j]);
          #pragma unroll
          for (int j = 0; j < 4; ++j) atomicAdd(d + 12 + j, ac3[j]);
        }
        curlr = lr;
        ac0 = ac1 = ac2 = ac3 = (f32x4)(0.f);
      }
      const short* p = xsrc + (size_t)s * DD + c0;
      bfx8 u = *reinterpret_cast<const bfx8*>(p);
      bfx8 v = *reinterpret_cast<const bfx8*>(p + 8);
      #pragma unroll
      for (int j = 0; j < 4; ++j) { ac0[j] += bf2f(u[j]); ac1[j] += bf2f(u[4 + j]); }
      #pragma unroll
      for (int j = 0; j < 4; ++j) { ac2[j] += bf2f(v[j]); ac3[j] += bf2f(v[4 + j]); }
    }
    if (curlr >= 0) {
      float* d = aggX + curlr * 132 + c0;
      #pragma unroll
      for (int j = 0; j < 4; ++j) atomicAdd(d + j,      ac0[j]);
      #pragma unroll
      for (int j = 0; j < 4; ++j) atomicAdd(d + 4 + j,  ac1[j]);
      #pragma unroll
      for (int j = 0; j < 4; ++j) atomicAdd(d + 8 + j,  ac2[j]);
      #pragma unroll
      for (int j = 0; j < 4; ++j) atomicAdd(d + 12 + j, ac3[j]);
    }
  }
  __syncthreads();

  // phase 2: agg = aggX @ Ws^T (wave owns cols wave*32..+32)
  {
    f32x4 acc[2][2];
    #pragma unroll
    for (int rf = 0; rf < 2; ++rf)
      #pragma unroll
      for (int c = 0; c < 2; ++c) acc[rf][c] = (f32x4)(0.f);
    #pragma unroll
    for (int ks = 0; ks < 4; ++ks) {
      bfx8 a0 = lds_frag(aggX, 0, ks, lane);
      bfx8 a1 = lds_frag(aggX, 16, ks, lane);
      #pragma unroll
      for (int c = 0; c < 2; ++c) {
        bfx8 b = load_pk(wsp, wave * 2 + c, ks, lane);
        acc[0][c] = __builtin_amdgcn_mfma_f32_16x16x32_bf16(a0, b, acc[0][c], 0, 0, 0);
        acc[1][c] = __builtin_amdgcn_mfma_f32_16x16x32_bf16(a1, b, acc[1][c], 0, 0, 0);
      }
    }
    const int lq = (lane >> 4) << 2;
    #pragma unroll
    for (int rf = 0; rf < 2; ++rf)
      #pragma unroll
      for (int c = 0; c < 2; ++c) {
        int col = wave * 32 + c * 16 + (lane & 15);
        #pragma unroll
        for (int q = 0; q < 4; ++q)
          aggl[(size_t)(rf * 16 + lq + q) * 132 + col] = acc[rf][c][q];
      }
  }
  __syncthreads();

  // phase 3: gi = xt@comb^T, gh = agg@whh^T
  f32x4 ai[2][2][3], ah[2][2][3];
  #pragma unroll
  for (int rf = 0; rf < 2; ++rf)
    #pragma unroll
    for (int c = 0; c < 2; ++c)
      #pragma unroll
      for (int g = 0; g < 3; ++g) { ai[rf][c][g] = (f32x4)(0.f); ah[rf][c][g] = (f32x4)(0.f); }
  #pragma unroll
  for (int ks = 0; ks < 4; ++ks) {
    bfx8 x0 = load_frag_clamp(xt, rbase,      ks * 32, lane);
    bfx8 x1 = load_frag_clamp(xt, rbase + 16, ks * 32, lane);
    bfx8 g0 = lds_frag(aggl, 0, ks, lane);
    bfx8 g1 = lds_frag(aggl, 16, ks, lane);
    #pragma unroll
    for (int g = 0; g < 3; ++g)
      #pragma unroll
      for (int c = 0; c < 2; ++c) {
        int ct = g * 8 + wave * 2 + c;
        bfx8 bi = load_pk(combp, ct, ks, lane);
        bfx8 bh = load_pk(whhp,  ct, ks, lane);
        ai[0][c][g] = __builtin_amdgcn_mfma_f32_16x16x32_bf16(x0, bi, ai[0][c][g], 0, 0, 0);
        ai[1][c][g] = __builtin_amdgcn_mfma_f32_16x16x32_bf16(x1, bi, ai[1][c][g], 0, 0, 0);
        ah[0][c][g] = __builtin_amdgcn_mfma_f32_16x16x32_bf16(g0, bh, ah[0][c][g], 0, 0, 0);
        ah[1][c][g] = __builtin_amdgcn_mfma_f32_16x16x32_bf16(g1, bh, ah[1][c][g], 0, 0, 0);
      }
  }

  // epilogue: gates -> res regs
  const int lq = (lane >> 4) << 2;
  #pragma unroll
  for (int c = 0; c < 2; ++c) {
    int col = wave * 32 + c * 16 + (lane & 15);
    float bir = bih[col], biz = bih[128 + col], bin = bih[256 + col];
    float bhr = bhh[col], bhz = bhh[128 + col], bhn = bhh[256 + col];
    #pragma unroll
    for (int rf = 0; rf < 2; ++rf)
      #pragma unroll
      for (int q = 0; q < 4; ++q) {
        int lrow = rf * 16 + lq + q;
        float ir = ai[rf][c][0][q] + bir, iz = ai[rf][c][1][q] + biz, in = ai[rf][c][2][q] + bin;
        float hr = ah[rf][c][0][q] + bhr, hz = ah[rf][c][1][q] + bhz, hn = ah[rf][c][2][q] + bhn;
        float rr = 1.f / (1.f + expf(-(ir + hr)));
        float zz = 1.f / (1.f + expf(-(iz + hz)));
        float nn = tanhf(in + rr * hn);
        float h  = aggl[(size_t)lrow * 132 + col];
        res[rf][c][q] = (1.f - zz) * nn + zz * h;
      }
  }
}

// ---------------- fused kernel: even blocks -> out_b (e1), odd -> out_a (e2+e3) ----------------
struct FArgs {
  const int* offs1; const uint32_t* bkt1;
  const int* offs2; const uint32_t* bkt2;
  const int* offs3; const uint32_t* bkt3;
  const short* xa; const short* xb;
  const short* wsp[3]; const short* combp[3]; const short* whhp[3];
  const float* bih[3]; const float* bhh[3];
  float* out_a; float* out_b;
};

__global__ __launch_bounds__(256) void k_fused(FArgs a) {
  __shared__ float aggX[32 * 132];
  __shared__ float aggl[32 * 132];
  const int wave = threadIdx.x >> 6, lane = threadIdx.x & 63;
  const int rbase = (blockIdx.x >> 1) * 32;
  const int isA = blockIdx.x & 1;
  f32x4 res[2][2];
  float* out;
  if (!isA) {
    unit(rbase, wave, lane, a.offs1, a.bkt1, a.xa, a.xb,
         a.wsp[0], a.combp[0], a.whhp[0], a.bih[0], a.bhh[0], aggX, aggl, res);
    out = a.out_b;
  } else {
    f32x4 res2[2][2];
    unit(rbase, wave, lane, a.offs2, a.bkt2, a.xb, a.xa,
         a.wsp[1], a.combp[1], a.whhp[1], a.bih[1], a.bhh[1], aggX, aggl, res);
    __syncthreads();
    unit(rbase, wave, lane, a.offs3, a.bkt3, a.xb, a.xa,
         a.wsp[2], a.combp[2], a.whhp[2], a.bih[2], a.bhh[2], aggX, aggl, res2);
    #pragma unroll
    for (int rf = 0; rf < 2; ++rf)
      #pragma unroll
      for (int c = 0; c < 2; ++c) res[rf][c] = (res[rf][c] + res2[rf][c]) * 0.5f;
    out = a.out_a;
  }
  const int lq = (lane >> 4) << 2;
  #pragma unroll
  for (int c = 0; c < 2; ++c) {
    int col = wave * 32 + c * 16 + (lane & 15);
    #pragma unroll
    for (int rf = 0; rf < 2; ++rf)
      #pragma unroll
      for (int q = 0; q < 4; ++q) {
        int r = rbase + rf * 16 + lq + q;
        if (r < NN) out[(size_t)r * DD + col] = fmaxf(res[rf][c][q], 0.f);
      }
  }
}

extern "C" void kernel_launch(void* const* d_in, const int* in_sizes, int n_in,
                              void* d_out, int out_size, void* d_ws, size_t ws_size,
                              hipStream_t stream) {
  const float* x_a = (const float*)d_in[0];
  const float* x_b = (const float*)d_in[1];
  const int* edges[3] = {(const int*)d_in[2], (const int*)d_in[3], (const int*)d_in[4]};
  const float *Ws[3], *Wt[3], *wih[3], *whh[3], *bih[3], *bhh[3];
  for (int e = 0; e < 3; ++e) {
    int b = 5 + e * 6;
    Ws[e]  = (const float*)d_in[b + 0];
    Wt[e]  = (const float*)d_in[b + 1];
    wih[e] = (const float*)d_in[b + 2];
    whh[e] = (const float*)d_in[b + 3];
    bih[e] = (const float*)d_in[b + 4];
    bhh[e] = (const float*)d_in[b + 5];
  }

  // workspace layout (~34 MB)
  char* ws = (char*)d_ws;
  short* xa_bf    = (short*)ws;                      // 12.8 MB
  short* xb_bf    = (short*)(ws + 12800000);         // 12.8 MB
  int*   counts   = (int*)(ws + 25600000);           // 3 x 200 KB
  int*   offs     = (int*)(ws + 26200000);           // 3 x 200 KB
  uint32_t* bucket= (uint32_t*)(ws + 26800000);      // 3 x 2 MB
  float* comb_f32 = (float*)(ws + 32800000);         // 3 x 192 KB
  short* pk       = (short*)(ws + 33400000);         // 3 x 224 KB
  float* combf[3]; short *wsp[3], *combp[3], *whhp[3];
  int *countsp[3], *offsp[3]; uint32_t* bktp[3];
  for (int e = 0; e < 3; ++e) {
    combf[e] = comb_f32 + (size_t)e * 49152;
    short* base = pk + (size_t)e * 114688;
    wsp[e] = base; combp[e] = base + 16384; whhp[e] = base + 65536;
    countsp[e] = counts + (size_t)e * 50000;
    offsp[e]   = offs + (size_t)e * 50000;
    bktp[e]    = bucket + (size_t)e * 500000;
  }

  // 1) convert x_a, x_b to bf16
  ConvJobs cj;
  cj.src[0] = x_a; cj.dst[0] = xa_bf;
  cj.src[1] = x_b; cj.dst[1] = xb_bf;
  hipLaunchKernelGGL(k_convert, dim3(6250, 2), dim3(256), 0, stream, cj);

  // 2) comb = wih @ Wt (f32)
  CombJobs cb;
  for (int e = 0; e < 3; ++e) { cb.wih[e] = wih[e]; cb.wt[e] = Wt[e]; cb.out[e] = combf[e]; }
  hipLaunchKernelGGL(k_comb, dim3(192, 3), dim3(256), 0, stream, cb);

  // 3) pack weights into fragment layout
  PackJobs pj;
  for (int e = 0; e < 3; ++e) {
    pj.src[e]     = Ws[e];     pj.dst[e]     = wsp[e];   pj.nct[e]     = 8;
    pj.src[3 + e] = combf[e];  pj.dst[3 + e] = combp[e]; pj.nct[3 + e] = 24;
    pj.src[6 + e] = whh[e];    pj.dst[6 + e] = whhp[e];  pj.nct[6 + e] = 24;
  }
  hipLaunchKernelGGL(k_pack, dim3(24, 9), dim3(256), 0, stream, pj);

  // 4) CSR build, batched over the 3 edge types
  CsrArgs ca;
  for (int e = 0; e < 3; ++e) {
    ca.edge[e] = edges[e]; ca.counts[e] = countsp[e];
    ca.offs[e] = offsp[e]; ca.bucket[e] = bktp[e];
  }
  (void)hipMemsetAsync(counts, 0, 3 * 50000 * sizeof(int), stream);
  const int EB = (EE + 255) / 256;
  hipLaunchKernelGGL(k_hist, dim3(EB, 3), dim3(256), 0, stream, ca);
  hipLaunchKernelGGL(k_scan, dim3(3), dim3(1024), 0, stream, ca);
  hipLaunchKernelGGL(k_fill, dim3(EB, 3), dim3(256), 0, stream, ca);

  // 5) fused compute
  float* out_a = (float*)d_out;
  float* out_b = (float*)d_out + (size_t)NN * DD;
  FArgs fa;
  fa.offs1 = offsp[0]; fa.bkt1 = bktp[0];
  fa.offs2 = offsp[1]; fa.bkt2 = bktp[1];
  fa.offs3 = offsp[2]; fa.bkt3 = bktp[2];
  fa.xa = xa_bf; fa.xb = xb_bf;
  for (int e = 0; e < 3; ++e) {
    fa.wsp[e] = wsp[e]; fa.combp[e] = combp[e]; fa.whhp[e] = whhp[e];
    fa.bih[e] = bih[e]; fa.bhh[e] = bhh[e];
  }
  fa.out_a = out_a; fa.out_b = out_b;
  hipLaunchKernelGGL(k_fused, dim3(ROWT * 2), dim3(256), 0, stream, fa);
}